// Round 1
// baseline (175.751 us; speedup 1.0000x reference)
//
#include <hip/hip_runtime.h>
#include <hip/hip_bf16.h>

// CrossAttention fused pipeline, MI355X (gfx950)
// B=2, N=160, D=4096, H=4, DH=1024, SCALE=1/32 (applied twice)
//
// Stage 1+2 (one kernel, grid.z): q = y@Wq^T (stored transposed per batch,
//   qT[b][d][n], bf16), k = x@Wk^T (row-major bf16)
// Stage 3: kkt[b,h,i,j] = SCALE * sum_d k[b,i,h*1024+d]*k[b,j,h*1024+d] (bf16)
// Stage 4: out[b,h,i,j] = softplus(SCALE * sum_m qT[b][i][m]*kkt[b,h,j,m]) (f32)

typedef __attribute__((ext_vector_type(4))) float  f32x4;
typedef __attribute__((ext_vector_type(8))) __bf16 bf16x8;

#define SCALE 0.03125f

static __device__ __forceinline__ f32x4 mfma16(bf16x8 a, bf16x8 b, f32x4 c) {
    return __builtin_amdgcn_mfma_f32_16x16x32_bf16(a, b, c, 0, 0, 0);
}

static __device__ __forceinline__ bf16x8 pack8(float4 a, float4 b) {
    bf16x8 r;
    r[0] = (__bf16)a.x; r[1] = (__bf16)a.y; r[2] = (__bf16)a.z; r[3] = (__bf16)a.w;
    r[4] = (__bf16)b.x; r[5] = (__bf16)b.y; r[6] = (__bf16)b.z; r[7] = (__bf16)b.w;
    return r;
}

static __device__ __forceinline__ float softplus(float x) {
    return fmaxf(x, 0.0f) + log1pf(expf(-fabsf(x)));
}

// ---------------------------------------------------------------------------
// Stage 1+2: C(320x4096) = A(320x4096) @ W^T, W is (4096x4096) row-major.
// Both operands are row-major along K -> identical fragment loads.
// BM=BN=BK=64, 256 threads (2x2 waves of 32x32), XOR-swizzled LDS.
// z==0: A=y, W=Wq, epilogue -> qT[b][col][row%160] bf16
// z==1: A=x, W=Wk, epilogue -> k[row][col] bf16
// ---------------------------------------------------------------------------
__global__ __launch_bounds__(256)
void qk_gemm(const float* __restrict__ y, const float* __restrict__ x,
             const float* __restrict__ Wq, const float* __restrict__ Wk,
             __bf16* __restrict__ qT, __bf16* __restrict__ kout)
{
    const bool isQ = (blockIdx.z == 0);
    const float* __restrict__ A = isQ ? y : x;
    const float* __restrict__ W = isQ ? Wq : Wk;

    __shared__ __bf16 lA[64 * 64];
    __shared__ __bf16 lB[64 * 64];

    const int tid  = threadIdx.x;
    const int lane = tid & 63;
    const int wid  = tid >> 6;
    const int wr   = wid >> 1;            // wave row 0..1
    const int wc   = wid & 1;             // wave col 0..1
    const int bm   = blockIdx.x * 64;     // 0..256
    const int bn   = blockIdx.y * 64;     // 0..4032

    const int sr  = tid >> 2;             // staging row 0..63
    const int sc  = (tid & 3) << 4;       // staging col (f32 units): 0,16,32,48
    const int swz = (sr & 7) << 3;        // XOR swizzle (bf16-index units)

    f32x4 acc[2][2] = {};

    const float* pa = A + (size_t)(bm + sr) * 4096 + sc;
    const float* pw = W + (size_t)(bn + sr) * 4096 + sc;

    for (int k0 = 0; k0 < 4096; k0 += 64) {
        float4 a0 = *(const float4*)(pa + k0);
        float4 a1 = *(const float4*)(pa + k0 + 4);
        float4 a2 = *(const float4*)(pa + k0 + 8);
        float4 a3 = *(const float4*)(pa + k0 + 12);
        float4 w0 = *(const float4*)(pw + k0);
        float4 w1 = *(const float4*)(pw + k0 + 4);
        float4 w2 = *(const float4*)(pw + k0 + 8);
        float4 w3 = *(const float4*)(pw + k0 + 12);

        __syncthreads();   // previous iteration's LDS reads done
        *(bf16x8*)&lA[(sr * 64 + sc) ^ swz]     = pack8(a0, a1);
        *(bf16x8*)&lA[(sr * 64 + sc + 8) ^ swz] = pack8(a2, a3);
        *(bf16x8*)&lB[(sr * 64 + sc) ^ swz]     = pack8(w0, w1);
        *(bf16x8*)&lB[(sr * 64 + sc + 8) ^ swz] = pack8(w2, w3);
        __syncthreads();

        #pragma unroll
        for (int kk = 0; kk < 64; kk += 32) {
            const int ko = kk + ((lane >> 4) << 3);
            bf16x8 af[2], bf[2];
            #pragma unroll
            for (int mr = 0; mr < 2; ++mr) {
                int row = wr * 32 + mr * 16 + (lane & 15);
                af[mr] = *(const bf16x8*)&lA[(row * 64 + ko) ^ ((row & 7) << 3)];
            }
            #pragma unroll
            for (int nr = 0; nr < 2; ++nr) {
                int row = wc * 32 + nr * 16 + (lane & 15);
                bf[nr] = *(const bf16x8*)&lB[(row * 64 + ko) ^ ((row & 7) << 3)];
            }
            #pragma unroll
            for (int mr = 0; mr < 2; ++mr)
                #pragma unroll
                for (int nr = 0; nr < 2; ++nr)
                    acc[mr][nr] = mfma16(af[mr], bf[nr], acc[mr][nr]);
        }
    }

    // Epilogue. C/D layout: col = lane&15, row = (lane>>4)*4 + r  [m89-verified]
    #pragma unroll
    for (int mr = 0; mr < 2; ++mr) {
        #pragma unroll
        for (int nr = 0; nr < 2; ++nr) {
            #pragma unroll
            for (int r = 0; r < 4; ++r) {
                int row = bm + wr * 32 + mr * 16 + ((lane >> 4) << 2) + r; // 0..319
                int col = bn + wc * 32 + nr * 16 + (lane & 15);           // 0..4095
                float v = acc[mr][nr][r];
                if (isQ) {
                    int b  = row >= 160;
                    int ri = row - b * 160;
                    qT[(size_t)b * 4096 * 160 + (size_t)col * 160 + ri] = (__bf16)v;
                } else {
                    kout[(size_t)row * 4096 + col] = (__bf16)v;
                }
            }
        }
    }
}

// ---------------------------------------------------------------------------
// Stage 3: kkt (symmetric). One wave per 16x16 output tile, K=1024.
// grid = (8 batches, 10, 10), 64 threads.
// ---------------------------------------------------------------------------
__global__ __launch_bounds__(64)
void kkt_kernel(const __bf16* __restrict__ kmat, __bf16* __restrict__ kkt)
{
    const int bh = blockIdx.x;            // b*4 + h
    const int b  = bh >> 2, h = bh & 3;
    const int i0 = blockIdx.y * 16;
    const int j0 = blockIdx.z * 16;
    const int lane = threadIdx.x;

    const __bf16* base = kmat + (size_t)b * 160 * 4096 + h * 1024;
    const int ko = (lane >> 4) << 3;
    const __bf16* pa = base + (size_t)(i0 + (lane & 15)) * 4096 + ko;
    const __bf16* pb = base + (size_t)(j0 + (lane & 15)) * 4096 + ko;

    f32x4 acc = {};
    #pragma unroll 4
    for (int kk = 0; kk < 1024; kk += 32) {
        bf16x8 a  = *(const bf16x8*)(pa + kk);
        bf16x8 bb = *(const bf16x8*)(pb + kk);
        acc = mfma16(a, bb, acc);
    }

    #pragma unroll
    for (int r = 0; r < 4; ++r) {
        int i = i0 + ((lane >> 4) << 2) + r;
        int j = j0 + (lane & 15);
        kkt[((size_t)bh * 160 + i) * 160 + j] = (__bf16)(acc[r] * SCALE);
    }
}

// ---------------------------------------------------------------------------
// Stage 4: dots + softplus. Per (b,h): C(4096x160) = qT[b] @ kkt[b,h]^T,
// both row-major along the contraction (m). 256 threads: 4 waves stacked in
// rows, each wave 16 rows x 32 cols (two 16x16 accumulators). K=160.
// ---------------------------------------------------------------------------
__global__ __launch_bounds__(256)
void dots_kernel(const __bf16* __restrict__ qT, const __bf16* __restrict__ kkt,
                 float* __restrict__ out)
{
    const int bh   = blockIdx.z;
    const int b    = bh >> 2;
    const int lane = threadIdx.x & 63;
    const int wid  = threadIdx.x >> 6;
    const int i0   = blockIdx.x * 64 + wid * 16;
    const int j0   = blockIdx.y * 32;

    const __bf16* Ab = qT + (size_t)b * 4096 * 160;
    const __bf16* Bb = kkt + (size_t)bh * 160 * 160;
    const int ko = (lane >> 4) << 3;
    const __bf16* pa  = Ab + (size_t)(i0 + (lane & 15)) * 160 + ko;
    const __bf16* pb0 = Bb + (size_t)(j0 + (lane & 15)) * 160 + ko;
    const __bf16* pb1 = pb0 + 16 * 160;

    f32x4 acc0 = {}, acc1 = {};
    #pragma unroll
    for (int m0 = 0; m0 < 160; m0 += 32) {
        bf16x8 a  = *(const bf16x8*)(pa + m0);
        bf16x8 b0 = *(const bf16x8*)(pb0 + m0);
        bf16x8 b1 = *(const bf16x8*)(pb1 + m0);
        acc0 = mfma16(a, b0, acc0);
        acc1 = mfma16(a, b1, acc1);
    }

    #pragma unroll
    for (int r = 0; r < 4; ++r) {
        int i = i0 + ((lane >> 4) << 2) + r;
        int j = j0 + (lane & 15);
        size_t o = ((size_t)bh * 4096 + i) * 160 + j;
        out[o]      = softplus(acc0[r] * SCALE);
        out[o + 16] = softplus(acc1[r] * SCALE);
    }
}

// ---------------------------------------------------------------------------
extern "C" void kernel_launch(void* const* d_in, const int* in_sizes, int n_in,
                              void* d_out, int out_size, void* d_ws, size_t ws_size,
                              hipStream_t stream)
{
    const float* x  = (const float*)d_in[0];
    const float* y  = (const float*)d_in[1];
    const float* Wq = (const float*)d_in[2];
    const float* Wk = (const float*)d_in[3];
    float* out = (float*)d_out;

    // workspace layout (bf16): qT [2*4096*160], k [320*4096], kkt [8*160*160]
    __bf16* qT  = (__bf16*)d_ws;
    __bf16* kbf = qT + (size_t)2 * 4096 * 160;
    __bf16* kkt = kbf + (size_t)320 * 4096;

    qk_gemm   <<<dim3(5, 64, 2),  256, 0, stream>>>(y, x, Wq, Wk, qT, kbf);
    kkt_kernel<<<dim3(8, 10, 10),  64, 0, stream>>>(kbf, kkt);
    dots_kernel<<<dim3(64, 5, 8), 256, 0, stream>>>(qT, kkt, out);
}

// Round 2
// 110.015 us; speedup vs baseline: 1.5975x; 1.5975x over previous
//
#include <hip/hip_runtime.h>
#include <hip/hip_bf16.h>

// CrossAttention fused pipeline, MI355X (gfx950)
// B=2, N=160, D=4096, H=4, DH=1024, SCALE=1/32 (applied twice)
//
// Stage 0: convert x,y f32 -> bf16 (L2-resident A operands)
// Stage 1+2 (weight-stationary GEMM, grid.y picks q/k):
//   q = y@Wq^T stored transposed qT[b][d][n] bf16; k = x@Wk^T row-major bf16.
//   Each block owns a 32-column W panel and the FULL M=320 -> W fetched once.
// Stage 3: kkt[b,h,i,j] = SCALE * k.k^T   (bf16)
// Stage 4: out = softplus(SCALE * qT @ kkt^T)  (f32)

typedef __attribute__((ext_vector_type(4))) float  f32x4;
typedef __attribute__((ext_vector_type(8))) __bf16 bf16x8;
typedef __attribute__((ext_vector_type(4))) __bf16 bf16x4;

#define SCALE 0.03125f

static __device__ __forceinline__ f32x4 mfma16(bf16x8 a, bf16x8 b, f32x4 c) {
    return __builtin_amdgcn_mfma_f32_16x16x32_bf16(a, b, c, 0, 0, 0);
}

static __device__ __forceinline__ bf16x8 pack8(float4 a, float4 b) {
    bf16x8 r;
    r[0] = (__bf16)a.x; r[1] = (__bf16)a.y; r[2] = (__bf16)a.z; r[3] = (__bf16)a.w;
    r[4] = (__bf16)b.x; r[5] = (__bf16)b.y; r[6] = (__bf16)b.z; r[7] = (__bf16)b.w;
    return r;
}

static __device__ __forceinline__ float softplus(float x) {
    return fmaxf(x, 0.0f) + log1pf(expf(-fabsf(x)));
}

static __device__ __forceinline__ void gload_lds16(const void* g, void* l) {
    __builtin_amdgcn_global_load_lds((const __attribute__((address_space(1))) void*)g,
                                     (__attribute__((address_space(3))) void*)l,
                                     16, 0, 0);
}

// ---------------------------------------------------------------------------
// Stage 0: f32 -> bf16 conversion of activations. grid (640, 2), 256 thr.
// ---------------------------------------------------------------------------
__global__ __launch_bounds__(256)
void cvt_kernel(const float* __restrict__ x, const float* __restrict__ y,
                __bf16* __restrict__ xb, __bf16* __restrict__ yb)
{
    const float* src = blockIdx.y ? y : x;
    __bf16* dst = blockIdx.y ? yb : xb;
    size_t i = ((size_t)blockIdx.x * 256 + threadIdx.x) * 8;
    float4 a = *(const float4*)(src + i);
    float4 b = *(const float4*)(src + i + 4);
    *(bf16x8*)(dst + i) = pack8(a, b);
}

// ---------------------------------------------------------------------------
// Stage 1+2: weight-stationary GEMM. C(320 x 4096) = A(320x4096,bf16) @ W^T.
// grid (128 panels of BN=32, 2 z), 512 threads = 8 waves (4M x 2N),
// per-wave 80x16 output. BK=64, double-buffered LDS, 1 barrier/step.
// A staged with global_load_lds (linear dest, inverse-XOR-swizzled source);
// W reg-staged f32->bf16 with next-step prefetch.
// ---------------------------------------------------------------------------
__global__ __launch_bounds__(512)
void qk_gemm(const __bf16* __restrict__ yb, const __bf16* __restrict__ xb,
             const float* __restrict__ Wq, const float* __restrict__ Wk,
             __bf16* __restrict__ qT, __bf16* __restrict__ kout)
{
    const bool isQ = (blockIdx.y == 0);
    const __bf16* __restrict__ Ab = isQ ? yb : xb;
    const float*  __restrict__ W  = isQ ? Wq : Wk;
    const int bn = blockIdx.x * 32;

    __shared__ __bf16 lA[2][320 * 64];
    __shared__ __bf16 lB[2][32 * 64];

    const int tid  = threadIdx.x;
    const int lane = tid & 63;
    const int wid  = tid >> 6;     // 0..7
    const int wr   = wid >> 1;     // 0..3 : M group of 80 rows
    const int wc   = wid & 1;      // 0..1 : N group of 16 cols

    // ---- A staging coords (global_load_lds, 5 issues of 512 lanes x 16B) ----
    // LDS is written linearly: byte = i*8192 + tid*16  -> row = i*64 + (tid>>3),
    // phys 16B-slot = tid&7.  Logical slot = phys ^ (row&7)  (inverse swizzle
    // applied on the GLOBAL source so the LDS read can use the same XOR).
    const int ar    = tid >> 3;                    // row (mod 64 rows per issue)
    const int aslot = (tid & 7) ^ (ar & 7);        // row&7 invariant across issues
    const __bf16* ag = Ab + (size_t)ar * 4096 + aslot * 8;

    // ---- W staging coords (reg path: one float4 per thread per step) ----
    const int brow = tid >> 4;                     // 0..31
    const int bslot = ((tid & 15) >> 1) ^ (brow & 7);
    const int bdst  = brow * 64 + bslot * 8 + (tid & 1) * 4;   // elem offset in lB
    const float* wg = W + (size_t)(bn + brow) * 4096 + (tid & 15) * 4;

    f32x4 acc[5] = {};

    // prologue: stage k0=0 into buf 0
    {
        #pragma unroll
        for (int i = 0; i < 5; ++i)
            gload_lds16(ag + (size_t)i * 64 * 4096,
                        (char*)&lA[0][0] + i * 8192 + wid * 1024);
        float4 w = *(const float4*)wg;
        bf16x4 bv; bv[0]=(__bf16)w.x; bv[1]=(__bf16)w.y; bv[2]=(__bf16)w.z; bv[3]=(__bf16)w.w;
        *(bf16x4*)&lB[0][bdst] = bv;
    }
    __syncthreads();

    int cur = 0;
    for (int s = 0; s < 64; ++s) {
        const int k0n = (s + 1) << 6;
        float4 wnext;
        if (s < 63) {
            const __bf16* agn = ag + k0n;
            #pragma unroll
            for (int i = 0; i < 5; ++i)
                gload_lds16(agn + (size_t)i * 64 * 4096,
                            (char*)&lA[cur ^ 1][0] + i * 8192 + wid * 1024);
            wnext = *(const float4*)(wg + k0n);
        }

        #pragma unroll
        for (int kk = 0; kk < 64; kk += 32) {
            const int ko = kk + ((lane >> 4) << 3);
            const int rb = wc * 16 + (lane & 15);
            bf16x8 bfrag = *(const bf16x8*)&lB[cur][rb * 64 + (ko ^ ((rb & 7) << 3))];
            #pragma unroll
            for (int m = 0; m < 5; ++m) {
                const int ra = wr * 80 + m * 16 + (lane & 15);
                bf16x8 afrag = *(const bf16x8*)&lA[cur][ra * 64 + (ko ^ ((ra & 7) << 3))];
                acc[m] = mfma16(afrag, bfrag, acc[m]);
            }
        }

        if (s < 63) {
            bf16x4 bv; bv[0]=(__bf16)wnext.x; bv[1]=(__bf16)wnext.y;
                      bv[2]=(__bf16)wnext.z; bv[3]=(__bf16)wnext.w;
            *(bf16x4*)&lB[cur ^ 1][bdst] = bv;
        }
        __syncthreads();
        cur ^= 1;
    }

    // Epilogue. C/D layout: col = lane&15, row = (lane>>4)*4 + r
    #pragma unroll
    for (int m = 0; m < 5; ++m) {
        const int row0 = wr * 80 + m * 16 + ((lane >> 4) << 2);
        const int col  = bn + wc * 16 + (lane & 15);
        #pragma unroll
        for (int r = 0; r < 4; ++r) {
            const int row = row0 + r;            // 0..319
            const float v = acc[m][r];
            if (isQ) {
                int b  = row >= 160;
                int ri = row - b * 160;
                qT[(size_t)b * 4096 * 160 + (size_t)col * 160 + ri] = (__bf16)v;
            } else {
                kout[(size_t)row * 4096 + col] = (__bf16)v;
            }
        }
    }
}

// ---------------------------------------------------------------------------
// Stage 3: kkt (symmetric). One wave per 16x16 output tile, K=1024.
// ---------------------------------------------------------------------------
__global__ __launch_bounds__(64)
void kkt_kernel(const __bf16* __restrict__ kmat, __bf16* __restrict__ kkt)
{
    const int bh = blockIdx.x;            // b*4 + h
    const int b  = bh >> 2, h = bh & 3;
    const int i0 = blockIdx.y * 16;
    const int j0 = blockIdx.z * 16;
    const int lane = threadIdx.x;

    const __bf16* base = kmat + (size_t)b * 160 * 4096 + h * 1024;
    const int ko = (lane >> 4) << 3;
    const __bf16* pa = base + (size_t)(i0 + (lane & 15)) * 4096 + ko;
    const __bf16* pb = base + (size_t)(j0 + (lane & 15)) * 4096 + ko;

    f32x4 acc = {};
    #pragma unroll 4
    for (int kk = 0; kk < 1024; kk += 32) {
        bf16x8 a  = *(const bf16x8*)(pa + kk);
        bf16x8 bb = *(const bf16x8*)(pb + kk);
        acc = mfma16(a, bb, acc);
    }

    #pragma unroll
    for (int r = 0; r < 4; ++r) {
        int i = i0 + ((lane >> 4) << 2) + r;
        int j = j0 + (lane & 15);
        kkt[((size_t)bh * 160 + i) * 160 + j] = (__bf16)(acc[r] * SCALE);
    }
}

// ---------------------------------------------------------------------------
// Stage 4: dots + softplus. Per (b,h): C(4096x160) = qT[b] @ kkt[b,h]^T. K=160.
// ---------------------------------------------------------------------------
__global__ __launch_bounds__(256)
void dots_kernel(const __bf16* __restrict__ qT, const __bf16* __restrict__ kkt,
                 float* __restrict__ out)
{
    const int bh   = blockIdx.z;
    const int b    = bh >> 2;
    const int lane = threadIdx.x & 63;
    const int wid  = threadIdx.x >> 6;
    const int i0   = blockIdx.x * 64 + wid * 16;
    const int j0   = blockIdx.y * 32;

    const __bf16* Ab = qT + (size_t)b * 4096 * 160;
    const __bf16* Bb = kkt + (size_t)bh * 160 * 160;
    const int ko = (lane >> 4) << 3;
    const __bf16* pa  = Ab + (size_t)(i0 + (lane & 15)) * 160 + ko;
    const __bf16* pb0 = Bb + (size_t)(j0 + (lane & 15)) * 160 + ko;
    const __bf16* pb1 = pb0 + 16 * 160;

    f32x4 acc0 = {}, acc1 = {};
    #pragma unroll
    for (int m0 = 0; m0 < 160; m0 += 32) {
        bf16x8 a  = *(const bf16x8*)(pa + m0);
        bf16x8 b0 = *(const bf16x8*)(pb0 + m0);
        bf16x8 b1 = *(const bf16x8*)(pb1 + m0);
        acc0 = mfma16(a, b0, acc0);
        acc1 = mfma16(a, b1, acc1);
    }

    #pragma unroll
    for (int r = 0; r < 4; ++r) {
        int i = i0 + ((lane >> 4) << 2) + r;
        int j = j0 + (lane & 15);
        size_t o = ((size_t)bh * 4096 + i) * 160 + j;
        out[o]      = softplus(acc0[r] * SCALE);
        out[o + 16] = softplus(acc1[r] * SCALE);
    }
}

// ---------------------------------------------------------------------------
extern "C" void kernel_launch(void* const* d_in, const int* in_sizes, int n_in,
                              void* d_out, int out_size, void* d_ws, size_t ws_size,
                              hipStream_t stream)
{
    const float* x  = (const float*)d_in[0];
    const float* y  = (const float*)d_in[1];
    const float* Wq = (const float*)d_in[2];
    const float* Wk = (const float*)d_in[3];
    float* out = (float*)d_out;

    // ws layout (bf16): qT[2*4096*160], k[320*4096], kkt[8*160*160],
    //                   xb[320*4096], yb[320*4096]   (~10.9 MB total)
    __bf16* qT  = (__bf16*)d_ws;
    __bf16* kbf = qT  + (size_t)2 * 4096 * 160;
    __bf16* kkt = kbf + (size_t)320 * 4096;
    __bf16* xb  = kkt + (size_t)8 * 160 * 160;
    __bf16* yb  = xb  + (size_t)320 * 4096;

    cvt_kernel <<<dim3(640, 2),   256, 0, stream>>>(x, y, xb, yb);
    qk_gemm    <<<dim3(128, 2),   512, 0, stream>>>(yb, xb, Wq, Wk, qT, kbf);
    kkt_kernel <<<dim3(8, 10, 10), 64, 0, stream>>>(kbf, kkt);
    dots_kernel<<<dim3(64, 5, 8), 256, 0, stream>>>(qT, kkt, out);
}

// Round 3
// 106.312 us; speedup vs baseline: 1.6532x; 1.0348x over previous
//
#include <hip/hip_runtime.h>
#include <hip/hip_bf16.h>

// CrossAttention fused pipeline, MI355X (gfx950)
// B=2, N=160, D=4096, H=4, DH=1024, SCALE=1/32 (applied twice)
//
// Stage 0: cvt x,y f32 -> bf16
// Stage 1+2: weight-stationary GEMM, K-split 2 (2 blocks/CU co-residency):
//   partials P[z][ks][320][4096] f32
// Stage 2b: reduce: P -> qT[b][d][n] bf16 (LDS transpose) and k[320][4096] bf16
// Stage 3: kkt = SCALE * k.k^T per (b,h)      (bf16)
// Stage 4: out = softplus(SCALE * qT @ kkt^T) (f32)

typedef __attribute__((ext_vector_type(4))) float  f32x4;
typedef __attribute__((ext_vector_type(8))) __bf16 bf16x8;
typedef __attribute__((ext_vector_type(4))) __bf16 bf16x4;

#define SCALE 0.03125f

static __device__ __forceinline__ f32x4 mfma16(bf16x8 a, bf16x8 b, f32x4 c) {
    return __builtin_amdgcn_mfma_f32_16x16x32_bf16(a, b, c, 0, 0, 0);
}

static __device__ __forceinline__ bf16x8 pack8(float4 a, float4 b) {
    bf16x8 r;
    r[0] = (__bf16)a.x; r[1] = (__bf16)a.y; r[2] = (__bf16)a.z; r[3] = (__bf16)a.w;
    r[4] = (__bf16)b.x; r[5] = (__bf16)b.y; r[6] = (__bf16)b.z; r[7] = (__bf16)b.w;
    return r;
}

static __device__ __forceinline__ bf16x8 pack8f(const float* v) {
    bf16x8 r;
    #pragma unroll
    for (int i = 0; i < 8; ++i) r[i] = (__bf16)v[i];
    return r;
}

static __device__ __forceinline__ float softplus(float x) {
    return fmaxf(x, 0.0f) + log1pf(expf(-fabsf(x)));
}

static __device__ __forceinline__ void gload_lds16(const void* g, void* l) {
    __builtin_amdgcn_global_load_lds((const __attribute__((address_space(1))) void*)g,
                                     (__attribute__((address_space(3))) void*)l,
                                     16, 0, 0);
}

// ---------------------------------------------------------------------------
// Stage 0: f32 -> bf16 conversion of activations. grid (640, 2), 256 thr.
// ---------------------------------------------------------------------------
__global__ __launch_bounds__(256)
void cvt_kernel(const float* __restrict__ x, const float* __restrict__ y,
                __bf16* __restrict__ xb, __bf16* __restrict__ yb)
{
    const float* src = blockIdx.y ? y : x;
    __bf16* dst = blockIdx.y ? yb : xb;
    size_t i = ((size_t)blockIdx.x * 256 + threadIdx.x) * 8;
    float4 a = *(const float4*)(src + i);
    float4 b = *(const float4*)(src + i + 4);
    *(bf16x8*)(dst + i) = pack8(a, b);
}

// ---------------------------------------------------------------------------
// Stage 1+2: weight-stationary GEMM with K-split 2.
// grid (128 panels BN=32, 2 z, 2 ksplit) = 512 blocks -> 2 blocks/CU.
// 256 threads = 4 waves, each wave 80 rows x 32 cols (5 A-frags x 2 B-frags).
// BK=32, double-buffered LDS (44 KB). Swizzle: 16B-slot ^= (row>>1)&3.
// Output: f32 partials P[(z*2+ks)][320][4096].
// ---------------------------------------------------------------------------
__global__ __launch_bounds__(256)
void qk_gemm(const __bf16* __restrict__ yb, const __bf16* __restrict__ xb,
             const float* __restrict__ Wq, const float* __restrict__ Wk,
             float* __restrict__ P)
{
    const int z  = blockIdx.y;            // 0: q (A=yb,W=Wq)  1: k (A=xb,W=Wk)
    const int ks = blockIdx.z;            // K-split half
    const __bf16* __restrict__ Ab = z ? xb : yb;
    const float*  __restrict__ W  = z ? Wk : Wq;
    const int bn = blockIdx.x * 32;
    const int kb = ks * 2048;             // K base

    __shared__ __bf16 lA[2][320 * 32];    // 20 KB each
    __shared__ __bf16 lB[2][32 * 32];     // 2 KB each

    const int tid  = threadIdx.x;
    const int lane = tid & 63;
    const int wid  = tid >> 6;            // 0..3 (M group of 80 rows)

    // ---- A staging (global_load_lds, 5 issues of 256 lanes x 16B) ----
    // linear LDS: issue i, byte = i*4096 + tid*16 -> row = i*64 + tid/4,
    // phys slot = tid&3. Inverse swizzle on the global source.
    const int ar    = tid >> 2;                       // row mod 64
    const int aslot = (tid & 3) ^ ((tid >> 3) & 3);   // (row>>1)&3 = (tid>>3)&3
    const __bf16* ag = Ab + (size_t)ar * 4096 + kb + aslot * 8;

    // ---- W staging (reg path: one float4 per thread per step) ----
    const int wrow  = tid >> 3;                       // 0..31
    const int chunk = tid & 7;                        // 4-f32 chunk
    const int bdst  = wrow * 32 + (((chunk >> 1) ^ ((wrow >> 1) & 3)) << 3)
                    + ((chunk & 1) << 2);             // bf16 elem index in lB
    const float* wg = W + (size_t)(bn + wrow) * 4096 + kb + chunk * 4;

    f32x4 acc[5][2] = {};

    // prologue: stage step 0 into buf 0
    {
        #pragma unroll
        for (int i = 0; i < 5; ++i)
            gload_lds16(ag + (size_t)i * 64 * 4096,
                        (char*)&lA[0][0] + i * 4096 + wid * 1024);
        float4 w = *(const float4*)wg;
        bf16x4 bv; bv[0]=(__bf16)w.x; bv[1]=(__bf16)w.y; bv[2]=(__bf16)w.z; bv[3]=(__bf16)w.w;
        *(bf16x4*)&lB[0][bdst] = bv;
    }
    __syncthreads();

    int cur = 0;
    for (int s = 0; s < 64; ++s) {
        float4 wnext;
        if (s < 63) {
            const __bf16* agn = ag + (s + 1) * 32;
            #pragma unroll
            for (int i = 0; i < 5; ++i)
                gload_lds16(agn + (size_t)i * 64 * 4096,
                            (char*)&lA[cur ^ 1][0] + i * 4096 + wid * 1024);
            wnext = *(const float4*)(wg + (s + 1) * 32);
        }

        const int c = lane >> 4;          // k-chunk 0..3
        bf16x8 bfr[2];
        #pragma unroll
        for (int jn = 0; jn < 2; ++jn) {
            const int j = jn * 16 + (lane & 15);
            bfr[jn] = *(const bf16x8*)&lB[cur][j * 32 + ((c ^ ((j >> 1) & 3)) << 3)];
        }
        #pragma unroll
        for (int m = 0; m < 5; ++m) {
            const int row = wid * 80 + m * 16 + (lane & 15);
            bf16x8 afr = *(const bf16x8*)&lA[cur][row * 32 + ((c ^ ((row >> 1) & 3)) << 3)];
            acc[m][0] = mfma16(afr, bfr[0], acc[m][0]);
            acc[m][1] = mfma16(afr, bfr[1], acc[m][1]);
        }

        if (s < 63) {
            bf16x4 bv; bv[0]=(__bf16)wnext.x; bv[1]=(__bf16)wnext.y;
                      bv[2]=(__bf16)wnext.z; bv[3]=(__bf16)wnext.w;
            *(bf16x4*)&lB[cur ^ 1][bdst] = bv;
        }
        __syncthreads();
        cur ^= 1;
    }

    // Epilogue: f32 partials. C/D layout: col = lane&15, row = (lane>>4)*4 + r
    float* Pz = P + ((size_t)(z * 2 + ks)) * 320 * 4096;
    #pragma unroll
    for (int m = 0; m < 5; ++m) {
        const int row0 = wid * 80 + m * 16 + ((lane >> 4) << 2);
        #pragma unroll
        for (int jn = 0; jn < 2; ++jn) {
            const int col = bn + jn * 16 + (lane & 15);
            #pragma unroll
            for (int r = 0; r < 4; ++r)
                Pz[(size_t)(row0 + r) * 4096 + col] = acc[m][jn][r];
        }
    }
}

// ---------------------------------------------------------------------------
// Stage 2b: reduce K-split partials -> qT (transposed bf16) and k (bf16).
// grid (64 col-tiles, 5 row-tiles, 2 z), 256 threads, 64x64 tiles.
// ---------------------------------------------------------------------------
__global__ __launch_bounds__(256)
void reduce_kernel(const float* __restrict__ P,
                   __bf16* __restrict__ qT, __bf16* __restrict__ kout)
{
    const int z    = blockIdx.z;
    const int col0 = blockIdx.x * 64;
    const int row0 = blockIdx.y * 64;
    const float* P0 = P + ((size_t)z * 2 + 0) * 320 * 4096;
    const float* P1 = P + ((size_t)z * 2 + 1) * 320 * 4096;

    const int t  = threadIdx.x;
    const int r  = t >> 2;                // 0..63
    const int cc = (t & 3) * 16;          // 0,16,32,48

    float v[16];
    {
        size_t base = (size_t)(row0 + r) * 4096 + col0 + cc;
        #pragma unroll
        for (int i = 0; i < 4; ++i) {
            float4 a = *(const float4*)(P0 + base + i * 4);
            float4 b = *(const float4*)(P1 + base + i * 4);
            v[i*4+0] = a.x + b.x; v[i*4+1] = a.y + b.y;
            v[i*4+2] = a.z + b.z; v[i*4+3] = a.w + b.w;
        }
    }

    if (z == 1) {  // k: row-major, direct
        __bf16* dst = kout + (size_t)(row0 + r) * 4096 + col0 + cc;
        *(bf16x8*)dst       = pack8f(v);
        *(bf16x8*)(dst + 8) = pack8f(v + 8);
        return;
    }

    // q: transpose via LDS -> qT[b][col][ri]
    __shared__ float lt[64][65];
    #pragma unroll
    for (int i = 0; i < 16; ++i) lt[r][cc + i] = v[i];
    __syncthreads();

    const int col = t & 63;
    const int rr0 = (t >> 6) * 16;
    float w[16];
    #pragma unroll
    for (int i = 0; i < 16; ++i) w[i] = lt[rr0 + i][col];

    const int gr = row0 + rr0;            // multiple of 16; never straddles 160
    const int b  = gr >= 160;
    const int ri = gr - b * 160;
    __bf16* dst = qT + (size_t)b * 4096 * 160 + (size_t)(col0 + col) * 160 + ri;
    *(bf16x8*)dst       = pack8f(w);
    *(bf16x8*)(dst + 8) = pack8f(w + 8);
}

// ---------------------------------------------------------------------------
// Stage 3: kkt (symmetric). One wave per 16x16 output tile, K=1024.
// ---------------------------------------------------------------------------
__global__ __launch_bounds__(64)
void kkt_kernel(const __bf16* __restrict__ kmat, __bf16* __restrict__ kkt)
{
    const int bh = blockIdx.x;            // b*4 + h
    const int b  = bh >> 2, h = bh & 3;
    const int i0 = blockIdx.y * 16;
    const int j0 = blockIdx.z * 16;
    const int lane = threadIdx.x;

    const __bf16* base = kmat + (size_t)b * 160 * 4096 + h * 1024;
    const int ko = (lane >> 4) << 3;
    const __bf16* pa = base + (size_t)(i0 + (lane & 15)) * 4096 + ko;
    const __bf16* pb = base + (size_t)(j0 + (lane & 15)) * 4096 + ko;

    f32x4 acc = {};
    #pragma unroll 4
    for (int kk = 0; kk < 1024; kk += 32) {
        bf16x8 a  = *(const bf16x8*)(pa + kk);
        bf16x8 bb = *(const bf16x8*)(pb + kk);
        acc = mfma16(a, bb, acc);
    }

    #pragma unroll
    for (int r = 0; r < 4; ++r) {
        int i = i0 + ((lane >> 4) << 2) + r;
        int j = j0 + (lane & 15);
        kkt[((size_t)bh * 160 + i) * 160 + j] = (__bf16)(acc[r] * SCALE);
    }
}

// ---------------------------------------------------------------------------
// Stage 4: dots + softplus. Per (b,h): C(4096x160) = qT[b] @ kkt[b,h]^T. K=160.
// ---------------------------------------------------------------------------
__global__ __launch_bounds__(256)
void dots_kernel(const __bf16* __restrict__ qT, const __bf16* __restrict__ kkt,
                 float* __restrict__ out)
{
    const int bh   = blockIdx.z;
    const int b    = bh >> 2;
    const int lane = threadIdx.x & 63;
    const int wid  = threadIdx.x >> 6;
    const int i0   = blockIdx.x * 64 + wid * 16;
    const int j0   = blockIdx.y * 32;

    const __bf16* Ab = qT + (size_t)b * 4096 * 160;
    const __bf16* Bb = kkt + (size_t)bh * 160 * 160;
    const int ko = (lane >> 4) << 3;
    const __bf16* pa  = Ab + (size_t)(i0 + (lane & 15)) * 160 + ko;
    const __bf16* pb0 = Bb + (size_t)(j0 + (lane & 15)) * 160 + ko;
    const __bf16* pb1 = pb0 + 16 * 160;

    f32x4 acc0 = {}, acc1 = {};
    #pragma unroll
    for (int m0 = 0; m0 < 160; m0 += 32) {
        bf16x8 a  = *(const bf16x8*)(pa + m0);
        bf16x8 b0 = *(const bf16x8*)(pb0 + m0);
        bf16x8 b1 = *(const bf16x8*)(pb1 + m0);
        acc0 = mfma16(a, b0, acc0);
        acc1 = mfma16(a, b1, acc1);
    }

    #pragma unroll
    for (int r = 0; r < 4; ++r) {
        int i = i0 + ((lane >> 4) << 2) + r;
        int j = j0 + (lane & 15);
        size_t o = ((size_t)bh * 4096 + i) * 160 + j;
        out[o]      = softplus(acc0[r] * SCALE);
        out[o + 16] = softplus(acc1[r] * SCALE);
    }
}

// ---------------------------------------------------------------------------
extern "C" void kernel_launch(void* const* d_in, const int* in_sizes, int n_in,
                              void* d_out, int out_size, void* d_ws, size_t ws_size,
                              hipStream_t stream)
{
    const float* x  = (const float*)d_in[0];
    const float* y  = (const float*)d_in[1];
    const float* Wq = (const float*)d_in[2];
    const float* Wk = (const float*)d_in[3];
    float* out = (float*)d_out;

    // ws layout: bf16 qT[2*4096*160], k[320*4096], kkt[8*160*160],
    //            xb[320*4096], yb[320*4096]; then f32 P[4][320*4096] (21 MB)
    __bf16* qT  = (__bf16*)d_ws;
    __bf16* kbf = qT  + (size_t)2 * 4096 * 160;
    __bf16* kkt = kbf + (size_t)320 * 4096;
    __bf16* xb  = kkt + (size_t)8 * 160 * 160;
    __bf16* yb  = xb  + (size_t)320 * 4096;
    float*  P   = (float*)(yb + (size_t)320 * 4096);
    // align P to 16 bytes
    P = (float*)(((uintptr_t)P + 15) & ~(uintptr_t)15);

    cvt_kernel   <<<dim3(640, 2),    256, 0, stream>>>(x, y, xb, yb);
    qk_gemm      <<<dim3(128, 2, 2), 256, 0, stream>>>(yb, xb, Wq, Wk, P);
    reduce_kernel<<<dim3(64, 5, 2),  256, 0, stream>>>(P, qT, kbf);
    kkt_kernel   <<<dim3(8, 10, 10),  64, 0, stream>>>(kbf, kkt);
    dots_kernel  <<<dim3(64, 5, 8),  256, 0, stream>>>(qT, kkt, out);
}

// Round 4
// 100.337 us; speedup vs baseline: 1.7516x; 1.0596x over previous
//
#include <hip/hip_runtime.h>
#include <hip/hip_bf16.h>

// CrossAttention fused pipeline, MI355X (gfx950)
// B=2, N=160, D=4096, H=4, DH=1024, SCALE=1/32 (applied twice)
//
// Stage 0: cvt x,y f32 -> bf16
// Stage 1+2: weight-stationary GEMM, K-split 2, T3/T4 pipeline:
//   triple-buffered A (global_load_lds), counted vmcnt, raw s_barrier.
//   partials P[z*2+ks][320][4096] f32
// Stage 2b: reduce: P -> qT[b][d][n] bf16 (LDS transpose) and k[320][4096] bf16
// Stage 3: kkt = SCALE * k.k^T per (b,h)      (bf16)
// Stage 4: out = softplus(SCALE * qT @ kkt^T) (f32)

typedef __attribute__((ext_vector_type(4))) float  f32x4;
typedef __attribute__((ext_vector_type(8))) __bf16 bf16x8;
typedef __attribute__((ext_vector_type(4))) __bf16 bf16x4;

#define SCALE 0.03125f

static __device__ __forceinline__ f32x4 mfma16(bf16x8 a, bf16x8 b, f32x4 c) {
    return __builtin_amdgcn_mfma_f32_16x16x32_bf16(a, b, c, 0, 0, 0);
}

static __device__ __forceinline__ bf16x8 pack8(float4 a, float4 b) {
    bf16x8 r;
    r[0] = (__bf16)a.x; r[1] = (__bf16)a.y; r[2] = (__bf16)a.z; r[3] = (__bf16)a.w;
    r[4] = (__bf16)b.x; r[5] = (__bf16)b.y; r[6] = (__bf16)b.z; r[7] = (__bf16)b.w;
    return r;
}

static __device__ __forceinline__ bf16x8 pack8f(const float* v) {
    bf16x8 r;
    #pragma unroll
    for (int i = 0; i < 8; ++i) r[i] = (__bf16)v[i];
    return r;
}

static __device__ __forceinline__ float softplus(float x) {
    return fmaxf(x, 0.0f) + log1pf(expf(-fabsf(x)));
}

static __device__ __forceinline__ void gload_lds16(const void* g, void* l) {
    __builtin_amdgcn_global_load_lds((const __attribute__((address_space(1))) void*)g,
                                     (__attribute__((address_space(3))) void*)l,
                                     16, 0, 0);
}

// ---------------------------------------------------------------------------
// Stage 0: f32 -> bf16 conversion of activations. grid (640, 2), 256 thr.
// ---------------------------------------------------------------------------
__global__ __launch_bounds__(256)
void cvt_kernel(const float* __restrict__ x, const float* __restrict__ y,
                __bf16* __restrict__ xb, __bf16* __restrict__ yb)
{
    const float* src = blockIdx.y ? y : x;
    __bf16* dst = blockIdx.y ? yb : xb;
    size_t i = ((size_t)blockIdx.x * 256 + threadIdx.x) * 8;
    float4 a = *(const float4*)(src + i);
    float4 b = *(const float4*)(src + i + 4);
    *(bf16x8*)(dst + i) = pack8(a, b);
}

// ---------------------------------------------------------------------------
// Stage 1+2: weight-stationary GEMM, K-split 2, counted-vmcnt pipeline.
// grid (128 panels BN=32, 2 z, 2 ksplit) = 512 blocks -> 2 blocks/CU.
// 256 threads = 4 waves, each wave 80 rows x 32 cols. BK=32, 64 steps.
// A: triple-buffered LDS via global_load_lds (pre-swizzled source);
// W: reg-prefetched 2 steps ahead, ds_written bf16 one step ahead.
// Per step exactly 6 VMEM issues; end-of-step s_waitcnt vmcnt(6) keeps the
// next-next tile's loads in flight across the raw s_barrier (T3+T4).
// ---------------------------------------------------------------------------
__global__ __launch_bounds__(256)
void qk_gemm(const __bf16* __restrict__ yb, const __bf16* __restrict__ xb,
             const float* __restrict__ Wq, const float* __restrict__ Wk,
             float* __restrict__ P)
{
    const int z  = blockIdx.y;            // 0: q (A=yb,W=Wq)  1: k (A=xb,W=Wk)
    const int ks = blockIdx.z;            // K-split half
    const __bf16* __restrict__ Ab = z ? xb : yb;
    const float*  __restrict__ W  = z ? Wk : Wq;
    const int bn = blockIdx.x * 32;
    const int kb = ks * 2048;             // K base

    __shared__ __bf16 lA[3 * 320 * 32];   // 3 x 20 KB
    __shared__ __bf16 lB[2 * 32 * 32];    // 2 x 2 KB

    const int tid  = threadIdx.x;
    const int lane = tid & 63;
    const int wid  = tid >> 6;            // 0..3 (M group of 80 rows)

    // ---- A staging: 5 gload_lds of 256 lanes x 16B per step ----
    // linear LDS: issue i, byte = i*4096 + tid*16 -> row ar = i*64 + tid/4,
    // phys 16B-slot = tid&3. Inverse swizzle applied on the global source:
    // aslot = phys ^ ((ar>>1)&3)   ((ar>>1)&3 == (tid>>3)&3, i-invariant)
    const int ar    = tid >> 2;
    const int aslot = (tid & 3) ^ ((tid >> 3) & 3);
    const __bf16* ag = Ab + (size_t)ar * 4096 + kb + aslot * 8;

    // ---- W staging: one float4 per thread per step ----
    const int wrow  = tid >> 3;                       // 0..31
    const int chunk = tid & 7;                        // 4-f32 chunk
    const int bofs  = wrow * 64 + (((chunk >> 1) ^ ((wrow >> 1) & 3)) << 4)
                    + ((chunk & 1) << 3);             // byte offset in lB buf
    const float* wg = W + (size_t)(bn + wrow) * 4096 + kb + chunk * 4;

    char* LA = (char*)lA;
    char* LB = (char*)lB;

    f32x4 acc[5][2] = {};

    // ---- prologue: stage steps 0 and 1 ----
    #pragma unroll
    for (int i = 0; i < 5; ++i)
        gload_lds16(ag + (size_t)i * 64 * 4096, LA + i * 4096 + wid * 1024);
    float4 w0 = *(const float4*)wg;
    #pragma unroll
    for (int i = 0; i < 5; ++i)
        gload_lds16(ag + 32 + (size_t)i * 64 * 4096, LA + 20480 + i * 4096 + wid * 1024);
    float4 w1 = *(const float4*)(wg + 32);

    asm volatile("s_waitcnt vmcnt(6)" ::: "memory");   // step-0 loads done
    {
        bf16x4 bv; bv[0]=(__bf16)w0.x; bv[1]=(__bf16)w0.y;
                   bv[2]=(__bf16)w0.z; bv[3]=(__bf16)w0.w;
        *(bf16x4*)(LB + bofs) = bv;                    // W(0) -> bB[0]
    }
    asm volatile("s_waitcnt lgkmcnt(0)" ::: "memory");
    __builtin_amdgcn_s_barrier();

    int a_cur = 0, a_nxt = 20480, a_nx2 = 40960;       // byte offsets (buf = 20480)
    int b_cur = 0, b_nxt = 2048;
    float4 wcur = w1;                                  // holds W(s+1)

    const int c4 = (lane >> 4) << 4;                   // k-chunk byte offset

    for (int s = 0; s < 64; ++s) {
        // -- ds_read fragments for step s --
        bf16x8 bfr[2];
        #pragma unroll
        for (int jn = 0; jn < 2; ++jn) {
            int j = jn * 16 + (lane & 15);
            bfr[jn] = *(const bf16x8*)(LB + b_cur + j * 64 + (c4 ^ (((j >> 1) & 3) << 4)));
        }
        bf16x8 afr[5];
        #pragma unroll
        for (int m = 0; m < 5; ++m) {
            int row = wid * 80 + m * 16 + (lane & 15);
            afr[m] = *(const bf16x8*)(LA + a_cur + row * 64 + (c4 ^ (((row >> 1) & 3) << 4)));
        }

        // -- issue exactly 6 VMEM for step s+2 --
        float4 wnew = wcur;
        if (s < 62) {
            const __bf16* agp = ag + (s + 2) * 32;
            #pragma unroll
            for (int i = 0; i < 5; ++i)
                gload_lds16(agp + (size_t)i * 64 * 4096, LA + a_nx2 + i * 4096 + wid * 1024);
            wnew = *(const float4*)(wg + (s + 2) * 32);
        }

        __builtin_amdgcn_s_setprio(1);
        #pragma unroll
        for (int m = 0; m < 5; ++m) {
            acc[m][0] = mfma16(afr[m], bfr[0], acc[m][0]);
            acc[m][1] = mfma16(afr[m], bfr[1], acc[m][1]);
        }
        __builtin_amdgcn_s_setprio(0);

        if (s < 63) {
            // write W(s+1) (loaded in step s-1) into the other B buffer
            bf16x4 bv; bv[0]=(__bf16)wcur.x; bv[1]=(__bf16)wcur.y;
                       bv[2]=(__bf16)wcur.z; bv[3]=(__bf16)wcur.w;
            *(bf16x4*)(LB + b_nxt + bofs) = bv;
            if (s < 62) asm volatile("s_waitcnt vmcnt(6) lgkmcnt(0)" ::: "memory");
            else        asm volatile("s_waitcnt vmcnt(0) lgkmcnt(0)" ::: "memory");
            __builtin_amdgcn_s_barrier();
        }

        // rotate buffers / regs
        int t = a_cur; a_cur = a_nxt; a_nxt = a_nx2; a_nx2 = t;
        t = b_cur; b_cur = b_nxt; b_nxt = t;
        wcur = wnew;
    }

    // Epilogue: f32 partials. C/D layout: col = lane&15, row = (lane>>4)*4 + r
    float* Pz = P + ((size_t)(z * 2 + ks)) * 320 * 4096;
    #pragma unroll
    for (int m = 0; m < 5; ++m) {
        const int row0 = wid * 80 + m * 16 + ((lane >> 4) << 2);
        #pragma unroll
        for (int jn = 0; jn < 2; ++jn) {
            const int col = bn + jn * 16 + (lane & 15);
            #pragma unroll
            for (int r = 0; r < 4; ++r)
                Pz[(size_t)(row0 + r) * 4096 + col] = acc[m][jn][r];
        }
    }
}

// ---------------------------------------------------------------------------
// Stage 2b: reduce K-split partials -> qT (transposed bf16) and k (bf16).
// grid (64 col-tiles, 5 row-tiles, 2 z), 256 threads, 64x64 tiles.
// ---------------------------------------------------------------------------
__global__ __launch_bounds__(256)
void reduce_kernel(const float* __restrict__ P,
                   __bf16* __restrict__ qT, __bf16* __restrict__ kout)
{
    const int z    = blockIdx.z;
    const int col0 = blockIdx.x * 64;
    const int row0 = blockIdx.y * 64;
    const float* P0 = P + ((size_t)z * 2 + 0) * 320 * 4096;
    const float* P1 = P + ((size_t)z * 2 + 1) * 320 * 4096;

    const int t  = threadIdx.x;
    const int r  = t >> 2;                // 0..63
    const int cc = (t & 3) * 16;          // 0,16,32,48

    float v[16];
    {
        size_t base = (size_t)(row0 + r) * 4096 + col0 + cc;
        #pragma unroll
        for (int i = 0; i < 4; ++i) {
            float4 a = *(const float4*)(P0 + base + i * 4);
            float4 b = *(const float4*)(P1 + base + i * 4);
            v[i*4+0] = a.x + b.x; v[i*4+1] = a.y + b.y;
            v[i*4+2] = a.z + b.z; v[i*4+3] = a.w + b.w;
        }
    }

    if (z == 1) {  // k: row-major, direct
        __bf16* dst = kout + (size_t)(row0 + r) * 4096 + col0 + cc;
        *(bf16x8*)dst       = pack8f(v);
        *(bf16x8*)(dst + 8) = pack8f(v + 8);
        return;
    }

    // q: transpose via LDS -> qT[b][col][ri]
    __shared__ float lt[64][65];
    #pragma unroll
    for (int i = 0; i < 16; ++i) lt[r][cc + i] = v[i];
    __syncthreads();

    const int col = t & 63;
    const int rr0 = (t >> 6) * 16;
    float w[16];
    #pragma unroll
    for (int i = 0; i < 16; ++i) w[i] = lt[rr0 + i][col];

    const int gr = row0 + rr0;            // multiple of 16; never straddles 160
    const int b  = gr >= 160;
    const int ri = gr - b * 160;
    __bf16* dst = qT + (size_t)b * 4096 * 160 + (size_t)(col0 + col) * 160 + ri;
    *(bf16x8*)dst       = pack8f(w);
    *(bf16x8*)(dst + 8) = pack8f(w + 8);
}

// ---------------------------------------------------------------------------
// Stage 3: kkt (symmetric). One wave per 16x16 output tile, K=1024.
// ---------------------------------------------------------------------------
__global__ __launch_bounds__(64)
void kkt_kernel(const __bf16* __restrict__ kmat, __bf16* __restrict__ kkt)
{
    const int bh = blockIdx.x;            // b*4 + h
    const int b  = bh >> 2, h = bh & 3;
    const int i0 = blockIdx.y * 16;
    const int j0 = blockIdx.z * 16;
    const int lane = threadIdx.x;

    const __bf16* base = kmat + (size_t)b * 160 * 4096 + h * 1024;
    const int ko = (lane >> 4) << 3;
    const __bf16* pa = base + (size_t)(i0 + (lane & 15)) * 4096 + ko;
    const __bf16* pb = base + (size_t)(j0 + (lane & 15)) * 4096 + ko;

    f32x4 acc = {};
    #pragma unroll 4
    for (int kk = 0; kk < 1024; kk += 32) {
        bf16x8 a  = *(const bf16x8*)(pa + kk);
        bf16x8 bb = *(const bf16x8*)(pb + kk);
        acc = mfma16(a, bb, acc);
    }

    #pragma unroll
    for (int r = 0; r < 4; ++r) {
        int i = i0 + ((lane >> 4) << 2) + r;
        int j = j0 + (lane & 15);
        kkt[((size_t)bh * 160 + i) * 160 + j] = (__bf16)(acc[r] * SCALE);
    }
}

// ---------------------------------------------------------------------------
// Stage 4: dots + softplus. Per (b,h): C(4096x160) = qT[b] @ kkt[b,h]^T. K=160.
// ---------------------------------------------------------------------------
__global__ __launch_bounds__(256)
void dots_kernel(const __bf16* __restrict__ qT, const __bf16* __restrict__ kkt,
                 float* __restrict__ out)
{
    const int bh   = blockIdx.z;
    const int b    = bh >> 2;
    const int lane = threadIdx.x & 63;
    const int wid  = threadIdx.x >> 6;
    const int i0   = blockIdx.x * 64 + wid * 16;
    const int j0   = blockIdx.y * 32;

    const __bf16* Ab = qT + (size_t)b * 4096 * 160;
    const __bf16* Bb = kkt + (size_t)bh * 160 * 160;
    const int ko = (lane >> 4) << 3;
    const __bf16* pa  = Ab + (size_t)(i0 + (lane & 15)) * 160 + ko;
    const __bf16* pb0 = Bb + (size_t)(j0 + (lane & 15)) * 160 + ko;
    const __bf16* pb1 = pb0 + 16 * 160;

    f32x4 acc0 = {}, acc1 = {};
    #pragma unroll
    for (int m0 = 0; m0 < 160; m0 += 32) {
        bf16x8 a  = *(const bf16x8*)(pa + m0);
        bf16x8 b0 = *(const bf16x8*)(pb0 + m0);
        bf16x8 b1 = *(const bf16x8*)(pb1 + m0);
        acc0 = mfma16(a, b0, acc0);
        acc1 = mfma16(a, b1, acc1);
    }

    #pragma unroll
    for (int r = 0; r < 4; ++r) {
        int i = i0 + ((lane >> 4) << 2) + r;
        int j = j0 + (lane & 15);
        size_t o = ((size_t)bh * 4096 + i) * 160 + j;
        out[o]      = softplus(acc0[r] * SCALE);
        out[o + 16] = softplus(acc1[r] * SCALE);
    }
}

// ---------------------------------------------------------------------------
extern "C" void kernel_launch(void* const* d_in, const int* in_sizes, int n_in,
                              void* d_out, int out_size, void* d_ws, size_t ws_size,
                              hipStream_t stream)
{
    const float* x  = (const float*)d_in[0];
    const float* y  = (const float*)d_in[1];
    const float* Wq = (const float*)d_in[2];
    const float* Wk = (const float*)d_in[3];
    float* out = (float*)d_out;

    // ws layout: bf16 qT[2*4096*160], k[320*4096], kkt[8*160*160],
    //            xb[320*4096], yb[320*4096]; then f32 P[4][320*4096] (21 MB)
    __bf16* qT  = (__bf16*)d_ws;
    __bf16* kbf = qT  + (size_t)2 * 4096 * 160;
    __bf16* kkt = kbf + (size_t)320 * 4096;
    __bf16* xb  = kkt + (size_t)8 * 160 * 160;
    __bf16* yb  = xb  + (size_t)320 * 4096;
    float*  P   = (float*)(yb + (size_t)320 * 4096);
    P = (float*)(((uintptr_t)P + 15) & ~(uintptr_t)15);

    cvt_kernel   <<<dim3(640, 2),    256, 0, stream>>>(x, y, xb, yb);
    qk_gemm      <<<dim3(128, 2, 2), 256, 0, stream>>>(yb, xb, Wq, Wk, P);
    reduce_kernel<<<dim3(64, 5, 2),  256, 0, stream>>>(P, qT, kbf);
    kkt_kernel   <<<dim3(8, 10, 10),  64, 0, stream>>>(kbf, kkt);
    dots_kernel  <<<dim3(64, 5, 8),  256, 0, stream>>>(qT, kkt, out);
}